// Round 1
// baseline (436.276 us; speedup 1.0000x reference)
//
#include <hip/hip_runtime.h>

// Decoder_33208687133135 — fused Koopman decoder, MI355X (gfx950).
// Only the diagonal of s,t survives -> layer4 is a per-row dot with one W4
// column. ~292 GFLOP, f16 MFMA (absmax 0.0625 vs thr 0.2425).
//
// R4 post-mortem: 350 us main. MfmaUtil 40.8 (=143us MFMA-busy, AT the
// 16x16x32 issue floor), VALUBusy 46.7, WRITE_SIZE 82MB vs 0.5MB output:
// scratch spill. Cause: launch_bounds(512,4) -> 128-reg class; acc[4][4]
// =64 AGPR leaves 64 arch VGPRs for bb(32)+a(16)+addr -> spill.
// R5: 1024 threads / 16 waves, wave tile 64x32 -> acc[4][2]=32 regs.
// Total ~90 regs in the 128 class, no spill, same MFMA count / same L2
// weight traffic / same LDS. Occupancy unchanged (16 waves/CU).
// pack_weights: 8 elems/thread, f16x8 store (same element mapping).

typedef _Float16 f16;
typedef _Float16 f16x8 __attribute__((ext_vector_type(8)));
typedef float f32x4 __attribute__((ext_vector_type(4)));

#define WPACK_PER_NET 589824
#define OFF_W1 0
#define OFF_W2 32768
#define OFF_W3 294912
#define OFF_W4T 557056
#define WPACK_BYTES (2u * WPACK_PER_NET * sizeof(f16))  // 2.36 MB

// ---------------- prologue: pack weights fp32 -> f16 blocked -------------
// B-fragment (16x16x32): B[k][n] held as n=lane&15, k=8*(lane>>4)+j.
// Blocked flat index: ((kk*32 + nt)*64 + (n&15) + 16*((k>>3)&3))*8 + (k&7).
// Each thread handles 8 consecutive flat indices (j=0..7 of one (kk,nt,lane))
// -> 8 gather loads in flight, one 16B store. Mapping identical to R4.
__global__ void pack_weights(const float* __restrict__ sW1, const float* __restrict__ sW2,
                             const float* __restrict__ sW3, const float* __restrict__ sW4,
                             const float* __restrict__ tW1, const float* __restrict__ tW2,
                             const float* __restrict__ tW3, const float* __restrict__ tW4,
                             f16* __restrict__ dst) {
  int idx8 = (blockIdx.x * 256 + threadIdx.x) * 8;
  if (idx8 >= 2 * WPACK_PER_NET) return;
  int net = idx8 >= WPACK_PER_NET;
  int f = idx8 - net * WPACK_PER_NET;
  const float* W1 = net ? tW1 : sW1;
  const float* W2 = net ? tW2 : sW2;
  const float* W3 = net ? tW3 : sW3;
  const float* W4 = net ? tW4 : sW4;
  f16x8 o;
  if (f < OFF_W2) {               // W1: (64,512)
    int lane = (f >> 3) & 63, nt = (f >> 9) & 31, kk = f >> 14;
    int r0 = kk * 32 + (lane >> 4) * 8, c = nt * 16 + (lane & 15);
#pragma unroll
    for (int j = 0; j < 8; j++) o[j] = (f16)W1[(r0 + j) * 512 + c];
  } else if (f < OFF_W3) {        // W2: (512,512)
    int f2 = f - OFF_W2;
    int lane = (f2 >> 3) & 63, nt = (f2 >> 9) & 31, kk = f2 >> 14;
    int r0 = kk * 32 + (lane >> 4) * 8, c = nt * 16 + (lane & 15);
#pragma unroll
    for (int j = 0; j < 8; j++) o[j] = (f16)W2[(r0 + j) * 512 + c];
  } else if (f < OFF_W4T) {       // W3: (512,512)
    int f3 = f - OFF_W3;
    int lane = (f3 >> 3) & 63, nt = (f3 >> 9) & 31, kk = f3 >> 14;
    int r0 = kk * 32 + (lane >> 4) * 8, c = nt * 16 + (lane & 15);
#pragma unroll
    for (int j = 0; j < 8; j++) o[j] = (f16)W3[(r0 + j) * 512 + c];
  } else {                        // W4: (512,64) -> W4T[i][k], k consecutive
    int f4 = f - OFF_W4T;
    int i = f4 >> 9, k0 = f4 & 511;
#pragma unroll
    for (int j = 0; j < 8; j++) o[j] = (f16)W4[(k0 + j) * 64 + i];
  }
  *(f16x8*)(dst + net * WPACK_PER_NET + f) = o;
}

// A-fragment order index for activation element (m,k):
// chunk = (k>>5)*4 + (m>>4); lane = (m&15) + 16*((k>>3)&3); j = k&7.
__device__ __forceinline__ int aidx(int m, int k) {
  return (((k >> 5) * 4 + (m >> 4)) * 64 + (m & 15) + ((k >> 3) & 3) * 16) * 8 + (k & 7);
}

// tanh(x) = 1 - 2/(exp(2x)+1). 6 VALU inst (2 trans-pipe). Saturates
// correctly at +/-inf, no clamp needed.
__device__ __forceinline__ float fast_tanh(float x) {
  float e = __expf(x + x);
  return fmaf(-2.0f, __builtin_amdgcn_rcpf(e + 1.0f), 1.0f);
}

// Load the wave's 2 B-fragments (32 cols) for k-slice kk.
// PACKED: lane-contiguous 16B loads from the frag-blocked f16 buffer (L2).
// DIRECT: coalesced fp32 gather from row-major W, convert in regs.
// Global col-tile index = wave*2 + nt (wave owns cols [32w, 32w+32)).
template <bool PACKED>
__device__ __forceinline__ void load_b(const f16* __restrict__ Wblk,
                                       const float* __restrict__ Wraw,
                                       int kk, int wave, int lane, f16x8* bdst) {
  if (PACKED) {
#pragma unroll
    for (int nt = 0; nt < 2; nt++)
      bdst[nt] = *(const f16x8*)(Wblk + kk * 16384 + ((wave * 2 + nt) * 64 + lane) * 8);
  } else {
    int n0 = wave * 32 + (lane & 15);
    int kb = kk * 32 + (lane >> 4) * 8;
#pragma unroll
    for (int nt = 0; nt < 2; nt++) {
      f16x8 v;
#pragma unroll
      for (int j = 0; j < 8; j++) v[j] = (f16)Wraw[(kb + j) * 512 + n0 + nt * 16];
      bdst[nt] = v;
    }
  }
}

// One MLP layer: Hout(64x512) = tanh(Asrc(64xK) @ W(Kx512) + bias).
// 16 waves; wave w owns output cols [32w, 32w+32). Weights stream L2->VGPR,
// depth-1 alternating-buffer prefetch; no weight LDS, no intra-loop barriers.
// acc[4][2] = 32 regs -> whole wave state ~90 regs, fits the 128-reg class
// (launch_bounds(1024,4)) with headroom: no scratch spill (R4's 82MB WRITE).
template <int NS, bool PACKED>
__device__ __forceinline__ void mlp_layer(const f16* __restrict__ Wblk,
                                          const float* __restrict__ Wraw,
                                          const float* __restrict__ bias,
                                          const f16* Asrc, f16* Hout,
                                          int wave, int lane, int sbase) {
  f32x4 acc[4][2];
#pragma unroll
  for (int nt = 0; nt < 2; nt++) {
    float bv = bias[wave * 32 + nt * 16 + (lane & 15)];
#pragma unroll
    for (int mt = 0; mt < 4; mt++) acc[mt][nt] = f32x4{bv, bv, bv, bv};
  }

  f16x8 bb[2][2];
  load_b<PACKED>(Wblk, Wraw, 0, wave, lane, bb[0]);
#pragma unroll
  for (int kk = 0; kk < NS; kk++) {
    if (kk + 1 < NS) load_b<PACKED>(Wblk, Wraw, kk + 1, wave, lane, bb[(kk + 1) & 1]);
    const f16* ab = Asrc + kk * 2048 + lane * 8;  // + mt*512 per mt (imm)
    f16x8 a[4];
#pragma unroll
    for (int mt = 0; mt < 4; mt++) a[mt] = *(const f16x8*)(ab + mt * 512);
#pragma unroll
    for (int mt = 0; mt < 4; mt++)
#pragma unroll
      for (int nt = 0; nt < 2; nt++)
        acc[mt][nt] = __builtin_amdgcn_mfma_f32_16x16x32_f16(a[mt], bb[kk & 1][nt],
                                                             acc[mt][nt], 0, 0, 0);
  }
  __syncthreads();  // all waves done reading Asrc (may alias Hout)

  // C/D layout (m89/m91): col = wave*32 + nt*16 + (lane&15),
  // row = mt*16 + (lane>>4)*4 + r. Target A-frag elem index decomposes as
  // sbase(lane) + const(mt,nt,r)  [algebra re-derived for 32-col waves,
  // spot-checked vs aidx() at (w,l,mt,nt,r)=(0,17,1,1,2),(5,60,3,0,1)]:
  //   sbase = wave*2048 + (lane>>4)*32 + ((lane&15)>>3)*128 + (lane&7)
  //   const = mt*512 + nt*256 + r*8
  // -> ds_write_b16 with immediate offsets, zero per-store address VALU.
  f16* hb = Hout + sbase;
#pragma unroll
  for (int mt = 0; mt < 4; mt++)
#pragma unroll
    for (int nt = 0; nt < 2; nt++)
#pragma unroll
      for (int r = 0; r < 4; r++)
        hb[mt * 512 + nt * 256 + r * 8] = (f16)fast_tanh(acc[mt][nt][r]);
  __syncthreads();
}

template <bool PACKED>
__global__ __launch_bounds__(1024, 4) void decoder_main(
    const float* __restrict__ x, const float* __restrict__ koop,
    const f16* __restrict__ wpack,
    const float* __restrict__ sW1, const float* __restrict__ sW2,
    const float* __restrict__ sW3, const float* __restrict__ sW4,
    const float* __restrict__ tW1, const float* __restrict__ tW2,
    const float* __restrict__ tW3, const float* __restrict__ tW4,
    const float* __restrict__ sb1, const float* __restrict__ sb2,
    const float* __restrict__ sb3, const float* __restrict__ sb4,
    const float* __restrict__ tb1, const float* __restrict__ tb2,
    const float* __restrict__ tb3, const float* __restrict__ tb4,
    float* __restrict__ out) {
  __shared__ __align__(16) f16 ZA[4096];   // z tile, A-frag order (8 KB)
  __shared__ __align__(16) f16 HA[32768];  // activations (64 KB)
  __shared__ float redBuf[2][64];          // ds, dt
  // total 72.5 KB; 1024-thread block -> 1 WG/CU, 16 waves (4/SIMD, 128 regs)

  const int b = blockIdx.x;
  const int t = threadIdx.x;
  const int wave = t >> 6, lane = t & 63;
  const int sbase =
      wave * 2048 + (lane >> 4) * 32 + ((lane & 15) >> 3) * 128 + (lane & 7);

  // Stage z = koopman[b]^T as f16 A-fragments: z[d][l] = koop[b][l][d].
  const float* kb = koop + b * 4096;
#pragma unroll
  for (int i = 0; i < 4; i++) {
    int flat = t + 1024 * i;                // coalesced fp32 read
    ZA[aidx(flat & 63, flat >> 6)] = (f16)kb[flat];
  }
  __syncthreads();

  for (int net = 0; net < 2; net++) {
    const f16* wb = PACKED ? (wpack + net * WPACK_PER_NET) : (const f16*)0;
    const float* W1 = net ? tW1 : sW1;
    const float* W2 = net ? tW2 : sW2;
    const float* W3 = net ? tW3 : sW3;
    const float* W4 = net ? tW4 : sW4;
    const float* b1 = net ? tb1 : sb1;
    const float* b2 = net ? tb2 : sb2;
    const float* b3 = net ? tb3 : sb3;
    const float* b4 = net ? tb4 : sb4;
    mlp_layer<2, PACKED>(PACKED ? wb + OFF_W1 : 0, W1, b1, ZA, HA, wave, lane, sbase);
    mlp_layer<16, PACKED>(PACKED ? wb + OFF_W2 : 0, W2, b2, HA, HA, wave, lane, sbase);
    mlp_layer<16, PACKED>(PACKED ? wb + OFF_W3 : 0, W3, b3, HA, HA, wave, lane, sbase);

    // Diagonal epilogue: ds[i] = H3[i,:] . W4[:,i] + b4[i].
    // 16 threads per row (all 1024 threads active).
    int i = t >> 4, sub = t & 15;
    float p = 0.f;
#pragma unroll
    for (int q = 0; q < 4; q++) {
      int k0 = sub * 32 + q * 8;
      f16x8 hv = *(const f16x8*)&HA[aidx(i, k0)];
      if (PACKED) {
        f16x8 wv = *(const f16x8*)&wb[OFF_W4T + i * 512 + k0];
#pragma unroll
        for (int j = 0; j < 8; j++) p += (float)hv[j] * (float)wv[j];
      } else {
#pragma unroll
        for (int j = 0; j < 8; j++) p += (float)hv[j] * W4[(k0 + j) * 64 + i];
      }
    }
    p += __shfl_down(p, 8, 16);
    p += __shfl_down(p, 4, 16);
    p += __shfl_down(p, 2, 16);
    p += __shfl_down(p, 1, 16);
    if (sub == 0) redBuf[net][i] = p + b4[i];
    __syncthreads();
  }

  if (t < 64) {
    out[b * 64 + t] = (x[b * 64 + t] - redBuf[1][t]) * __expf(-redBuf[0][t]);
  }
}

extern "C" void kernel_launch(void* const* d_in, const int* in_sizes, int n_in,
                              void* d_out, int out_size, void* d_ws, size_t ws_size,
                              hipStream_t stream) {
  const float* x    = (const float*)d_in[0];
  const float* koop = (const float*)d_in[1];
  const float* sW1 = (const float*)d_in[2];  const float* sb1 = (const float*)d_in[3];
  const float* sW2 = (const float*)d_in[4];  const float* sb2 = (const float*)d_in[5];
  const float* sW3 = (const float*)d_in[6];  const float* sb3 = (const float*)d_in[7];
  const float* sW4 = (const float*)d_in[8];  const float* sb4 = (const float*)d_in[9];
  const float* tW1 = (const float*)d_in[10]; const float* tb1 = (const float*)d_in[11];
  const float* tW2 = (const float*)d_in[12]; const float* tb2 = (const float*)d_in[13];
  const float* tW3 = (const float*)d_in[14]; const float* tb3 = (const float*)d_in[15];
  const float* tW4 = (const float*)d_in[16]; const float* tb4 = (const float*)d_in[17];
  float* out = (float*)d_out;

  // Launch-invariant branch (ws_size constant across calls) -> graph-safe.
  // NEVER write past ws_size (R1: OOB pack corrupted harness allocations).
  if (ws_size >= (size_t)WPACK_BYTES) {
    f16* wpack = (f16*)d_ws;
    pack_weights<<<576, 256, 0, stream>>>(sW1, sW2, sW3, sW4, tW1, tW2, tW3, tW4, wpack);
    decoder_main<true><<<2048, 1024, 0, stream>>>(
        x, koop, wpack, sW1, sW2, sW3, sW4, tW1, tW2, tW3, tW4,
        sb1, sb2, sb3, sb4, tb1, tb2, tb3, tb4, out);
  } else {
    decoder_main<false><<<2048, 1024, 0, stream>>>(
        x, koop, (const f16*)0, sW1, sW2, sW3, sW4, tW1, tW2, tW3, tW4,
        sb1, sb2, sb3, sb4, tb1, tb2, tb3, tb4, out);
  }
}